// Round 1
// baseline (620.250 us; speedup 1.0000x reference)
//
#include <hip/hip_runtime.h>
#include <hip/hip_bf16.h>

typedef __attribute__((ext_vector_type(4))) float f32x4;
typedef __attribute__((ext_vector_type(8))) short short8;
typedef __attribute__((ext_vector_type(8))) unsigned short ushort8;

#define D 128
#define EPS 1e-8f

__device__ __forceinline__ short f2bf(float f) {
    unsigned int u = __float_as_uint(f);
    unsigned int r = (u + 0x7fffu + ((u >> 16) & 1u)) >> 16;  // RNE
    return (short)r;
}
__device__ __forceinline__ float bf2f(unsigned short u) {
    return __uint_as_float(((unsigned int)u) << 16);
}

// Convert W (f32, row-major DxD) to bf16
__global__ __launch_bounds__(256) void convw_kernel(const float* __restrict__ W,
                                                    short* __restrict__ Wbf) {
    int i = blockIdx.x * 256 + threadIdx.x;   // grid sized exactly D*D/256
    Wbf[i] = f2bf(W[i]);
}

// deg=1 (self loop), fill=relu(mask), z0=fill
__global__ __launch_bounds__(256) void init_kernel(const float* __restrict__ mask,
                                                   float* __restrict__ deg,
                                                   float* __restrict__ fill,
                                                   float* __restrict__ z0, int N) {
    int i = blockIdx.x * 256 + threadIdx.x;
    if (i < N) {
        deg[i] = 1.0f;
        float f = fmaxf(mask[i], 0.0f);
        fill[i] = f;
        z0[i] = f;
    }
}

// h = tanh(x @ W^T + b), row-normalized, stored bf16.
// Block = 256 threads = 4 waves; each wave computes a 16x128 row tile via
// 8 coltiles x 4 kchunks of mfma_f32_16x16x32_bf16.
__global__ __launch_bounds__(256) void gemm_kernel(const float* __restrict__ x,
                                                   const short* __restrict__ Wbf,
                                                   const float* __restrict__ b,
                                                   unsigned short* __restrict__ hn,
                                                   int N) {
    int tid  = threadIdx.x;
    int wave = tid >> 6;
    int lane = tid & 63;
    int l16  = lane & 15;
    int g    = lane >> 4;
    int r0   = blockIdx.x * 64 + wave * 16;

    // ---- A fragments: lane holds x[arow][kc*32 + g*8 .. +7] as bf16x8
    int arow = r0 + l16;
    if (arow >= N) arow = N - 1;           // clamp; invalid rows never stored
    short8 afr[4];
#pragma unroll
    for (int kc = 0; kc < 4; ++kc) {
        const float* xp = x + (size_t)arow * D + kc * 32 + g * 8;
        float4 lo = *(const float4*)xp;
        float4 hi = *(const float4*)(xp + 4);
        short8 a;
        a[0] = f2bf(lo.x); a[1] = f2bf(lo.y); a[2] = f2bf(lo.z); a[3] = f2bf(lo.w);
        a[4] = f2bf(hi.x); a[5] = f2bf(hi.y); a[6] = f2bf(hi.z); a[7] = f2bf(hi.w);
        afr[kc] = a;
    }

    f32x4 acc[8];
#pragma unroll
    for (int j = 0; j < 8; ++j) acc[j] = (f32x4){0.f, 0.f, 0.f, 0.f};

#pragma unroll
    for (int j = 0; j < 8; ++j) {
#pragma unroll
        for (int kc = 0; kc < 4; ++kc) {
            // B[k][n] = W[n][k]; lane: col n = j*16+l16, k = kc*32 + g*8 + t
            const short8* bp =
                (const short8*)(Wbf + ((size_t)(j * 16 + l16) * D + kc * 32 + g * 8));
            acc[j] = __builtin_amdgcn_mfma_f32_16x16x32_bf16(afr[kc], *bp, acc[j], 0, 0, 0);
        }
    }

    // ---- epilogue: bias + tanh, row sq-sums, normalize, store bf16
    // C/D layout: col = l16 (+j*16), row (within tile) = g*4 + r
    float tt[8][4];
    float sq[4] = {0.f, 0.f, 0.f, 0.f};
#pragma unroll
    for (int j = 0; j < 8; ++j) {
        float bj = b[j * 16 + l16];
#pragma unroll
        for (int r = 0; r < 4; ++r) {
            float t = tanhf(acc[j][r] + bj);
            tt[j][r] = t;
            sq[r] += t * t;
        }
    }
    // reduce over the 16 lanes sharing g (they cover all 128 cols)
#pragma unroll
    for (int m = 1; m <= 8; m <<= 1) {
#pragma unroll
        for (int r = 0; r < 4; ++r) sq[r] += __shfl_xor(sq[r], m);
    }
    float inv[4];
#pragma unroll
    for (int r = 0; r < 4; ++r) inv[r] = 1.0f / fmaxf(sqrtf(sq[r]), EPS);

#pragma unroll
    for (int r = 0; r < 4; ++r) {
        int row = r0 + g * 4 + r;
        if (row < N) {
#pragma unroll
            for (int j = 0; j < 8; ++j) {
                hn[(size_t)row * D + j * 16 + l16] =
                    (unsigned short)f2bf(tt[j][r] * inv[r]);
            }
        }
    }
}

// Edge weights: 16 lanes per edge; w = relu(dot(hn[s], hn[d])); deg[d] += w
__global__ __launch_bounds__(256) void edge_kernel(const int* __restrict__ src,
                                                   const int* __restrict__ dst,
                                                   const unsigned short* __restrict__ hn,
                                                   float* __restrict__ ew,
                                                   float* __restrict__ deg, int E) {
    int lane = threadIdx.x & 15;
    int grp  = (blockIdx.x * 256 + threadIdx.x) >> 4;
    int ngrp = (gridDim.x * 256) >> 4;
    for (int e = grp; e < E; e += ngrp) {
        int s = src[e], d = dst[e];
        ushort8 a = *((const ushort8*)(hn + (size_t)s * D) + lane);
        ushort8 c = *((const ushort8*)(hn + (size_t)d * D) + lane);
        float dot = 0.f;
#pragma unroll
        for (int t = 0; t < 8; ++t) dot += bf2f(a[t]) * bf2f(c[t]);
#pragma unroll
        for (int m = 8; m >= 1; m >>= 1) dot += __shfl_xor(dot, m);
        if (lane == 0) {
            float w = fmaxf(dot, 0.f);
            ew[e] = w;
            atomicAdd(deg + d, w);
        }
    }
}

// deg -> dinv in place
__global__ __launch_bounds__(256) void dinv_kernel(float* __restrict__ deg, int N) {
    int i = blockIdx.x * 256 + threadIdx.x;
    if (i < N) {
        float dg = deg[i];
        deg[i] = (dg > 0.f) ? rsqrtf(fmaxf(dg, EPS)) : 0.f;
    }
}

// normw[e] = (1-alpha) * dinv[src] * w[e] * dinv[dst]
__global__ __launch_bounds__(256) void normw_kernel(const int* __restrict__ src,
                                                    const int* __restrict__ dst,
                                                    const float* __restrict__ ew,
                                                    const float* __restrict__ dinv,
                                                    const float* __restrict__ alpha,
                                                    float* __restrict__ nw, int E) {
    int e = blockIdx.x * 256 + threadIdx.x;
    if (e < E) {
        float oma = 1.0f - alpha[0];
        nw[e] = oma * dinv[src[e]] * ew[e] * dinv[dst[e]];
    }
}

// z_out = alpha*fill + (1-alpha)*dinv^2*z_in   (self-loop folded in)
__global__ __launch_bounds__(256) void zinit_kernel(const float* __restrict__ fill,
                                                    const float* __restrict__ dinv,
                                                    const float* __restrict__ zin,
                                                    const float* __restrict__ alpha,
                                                    float* __restrict__ zout, int N) {
    int i = blockIdx.x * 256 + threadIdx.x;
    if (i < N) {
        float al = alpha[0];
        float di = dinv[i];
        zout[i] = al * fill[i] + (1.0f - al) * di * di * zin[i];
    }
}

// z_out[dst] += normw[e] * z_in[src]
__global__ __launch_bounds__(256) void scatter_kernel(const int* __restrict__ src,
                                                      const int* __restrict__ dst,
                                                      const float* __restrict__ nw,
                                                      const float* __restrict__ zin,
                                                      float* __restrict__ zout, int E) {
    int e = blockIdx.x * 256 + threadIdx.x;
    if (e < E) atomicAdd(zout + dst[e], nw[e] * zin[src[e]]);
}

__global__ __launch_bounds__(256) void copy_kernel(const float* __restrict__ zin,
                                                   float* __restrict__ out, int N) {
    int i = blockIdx.x * 256 + threadIdx.x;
    if (i < N) out[i] = zin[i];
}

extern "C" void kernel_launch(void* const* d_in, const int* in_sizes, int n_in,
                              void* d_out, int out_size, void* d_ws, size_t ws_size,
                              hipStream_t stream) {
    const float* x     = (const float*)d_in[0];
    const float* mask  = (const float*)d_in[1];
    const int*   ei    = (const int*)d_in[2];
    const float* W     = (const float*)d_in[3];
    const float* b     = (const float*)d_in[4];
    const float* alpha = (const float*)d_in[5];

    int N = in_sizes[1];          // mask is N x 1
    int E = in_sizes[2] / 2;      // edge_index is 2 x E
    const int* src = ei;
    const int* dst = ei + E;

    float* out = (float*)d_out;   // [0,N) = z ; [N, N+E) = edge_weights
    float* ew  = out + N;

    // workspace layout
    char* wsb = (char*)d_ws;
    unsigned short* hn = (unsigned short*)wsb;                 // N*D bf16
    short* Wbf = (short*)(wsb + (size_t)N * D * 2);            // D*D bf16
    float* deg  = (float*)((char*)Wbf + (size_t)D * D * 2);    // N  (becomes dinv)
    float* fill = deg + N;                                     // N
    float* zA   = fill + N;                                    // N
    float* zB   = zA + N;                                      // N
    float* nw   = zB + N;                                      // E

    int nb_n = (N + 255) / 256;
    int nb_e = (E + 255) / 256;

    convw_kernel<<<(D * D) / 256, 256, 0, stream>>>(W, Wbf);
    init_kernel<<<nb_n, 256, 0, stream>>>(mask, deg, fill, zA, N);
    gemm_kernel<<<(N + 63) / 64, 256, 0, stream>>>(x, Wbf, b, hn, N);
    edge_kernel<<<12800, 256, 0, stream>>>(src, dst, hn, ew, deg, E);
    dinv_kernel<<<nb_n, 256, 0, stream>>>(deg, N);
    normw_kernel<<<nb_e, 256, 0, stream>>>(src, dst, ew, deg, alpha, nw, E);

    float* zin = zA;
    float* zout = zB;
    for (int it = 0; it < 5; ++it) {
        zinit_kernel<<<nb_n, 256, 0, stream>>>(fill, deg, zin, alpha, zout, N);
        scatter_kernel<<<nb_e, 256, 0, stream>>>(src, dst, nw, zin, zout, E);
        float* tmp = zin; zin = zout; zout = tmp;
    }
    copy_kernel<<<nb_n, 256, 0, stream>>>(zin, out, N);
}

// Round 2
// 419.912 us; speedup vs baseline: 1.4771x; 1.4771x over previous
//
#include <hip/hip_runtime.h>
#include <hip/hip_bf16.h>

typedef __attribute__((ext_vector_type(4))) float f32x4;
typedef __attribute__((ext_vector_type(8))) short short8;
typedef __attribute__((ext_vector_type(8))) unsigned short ushort8;

#define D 128
#define EPS 1e-8f

__device__ __forceinline__ short f2bf(float f) {
    unsigned int u = __float_as_uint(f);
    unsigned int r = (u + 0x7fffu + ((u >> 16) & 1u)) >> 16;  // RNE
    return (short)r;
}
__device__ __forceinline__ float bf2f(unsigned short u) {
    return __uint_as_float(((unsigned int)u) << 16);
}

// Convert W (f32, row-major DxD) to bf16
__global__ __launch_bounds__(256) void convw_kernel(const float* __restrict__ W,
                                                    short* __restrict__ Wbf) {
    int i = blockIdx.x * 256 + threadIdx.x;   // grid sized exactly D*D/256
    Wbf[i] = f2bf(W[i]);
}

// deg=1 (self loop), fill=relu(mask), cnt=0
__global__ __launch_bounds__(256) void init_kernel(const float* __restrict__ mask,
                                                   float* __restrict__ deg,
                                                   float* __restrict__ fill,
                                                   int* __restrict__ cnt, int N) {
    int i = blockIdx.x * 256 + threadIdx.x;
    if (i < N) {
        deg[i] = 1.0f;
        fill[i] = fmaxf(mask[i], 0.0f);
        cnt[i] = 0;
    }
}

// h = tanh(x @ W^T + b), row-normalized, stored bf16.
__global__ __launch_bounds__(256) void gemm_kernel(const float* __restrict__ x,
                                                   const short* __restrict__ Wbf,
                                                   const float* __restrict__ b,
                                                   unsigned short* __restrict__ hn,
                                                   int N) {
    int tid  = threadIdx.x;
    int wave = tid >> 6;
    int lane = tid & 63;
    int l16  = lane & 15;
    int g    = lane >> 4;
    int r0   = blockIdx.x * 64 + wave * 16;

    int arow = r0 + l16;
    if (arow >= N) arow = N - 1;           // clamp; invalid rows never stored
    short8 afr[4];
#pragma unroll
    for (int kc = 0; kc < 4; ++kc) {
        const float* xp = x + (size_t)arow * D + kc * 32 + g * 8;
        float4 lo = *(const float4*)xp;
        float4 hi = *(const float4*)(xp + 4);
        short8 a;
        a[0] = f2bf(lo.x); a[1] = f2bf(lo.y); a[2] = f2bf(lo.z); a[3] = f2bf(lo.w);
        a[4] = f2bf(hi.x); a[5] = f2bf(hi.y); a[6] = f2bf(hi.z); a[7] = f2bf(hi.w);
        afr[kc] = a;
    }

    f32x4 acc[8];
#pragma unroll
    for (int j = 0; j < 8; ++j) acc[j] = (f32x4){0.f, 0.f, 0.f, 0.f};

#pragma unroll
    for (int j = 0; j < 8; ++j) {
#pragma unroll
        for (int kc = 0; kc < 4; ++kc) {
            const short8* bp =
                (const short8*)(Wbf + ((size_t)(j * 16 + l16) * D + kc * 32 + g * 8));
            acc[j] = __builtin_amdgcn_mfma_f32_16x16x32_bf16(afr[kc], *bp, acc[j], 0, 0, 0);
        }
    }

    // C/D layout: col = l16 (+j*16), row (within tile) = g*4 + r
    float tt[8][4];
    float sq[4] = {0.f, 0.f, 0.f, 0.f};
#pragma unroll
    for (int j = 0; j < 8; ++j) {
        float bj = b[j * 16 + l16];
#pragma unroll
        for (int r = 0; r < 4; ++r) {
            float t = tanhf(acc[j][r] + bj);
            tt[j][r] = t;
            sq[r] += t * t;
        }
    }
#pragma unroll
    for (int m = 1; m <= 8; m <<= 1) {
#pragma unroll
        for (int r = 0; r < 4; ++r) sq[r] += __shfl_xor(sq[r], m);
    }
    float inv[4];
#pragma unroll
    for (int r = 0; r < 4; ++r) inv[r] = 1.0f / fmaxf(sqrtf(sq[r]), EPS);

#pragma unroll
    for (int r = 0; r < 4; ++r) {
        int row = r0 + g * 4 + r;
        if (row < N) {
#pragma unroll
            for (int j = 0; j < 8; ++j) {
                hn[(size_t)row * D + j * 16 + l16] =
                    (unsigned short)f2bf(tt[j][r] * inv[r]);
            }
        }
    }
}

// Edge weights: one 16-lane group per edge (exact grid, max MLP).
// w = relu(dot(hn[s], hn[d])); deg[d] += w; cnt[d] += 1 (histogram for CSR)
__global__ __launch_bounds__(256) void edge_kernel(const int* __restrict__ src,
                                                   const int* __restrict__ dst,
                                                   const unsigned short* __restrict__ hn,
                                                   float* __restrict__ ew,
                                                   float* __restrict__ deg,
                                                   int* __restrict__ cnt, int E) {
    int g    = (blockIdx.x * 256 + threadIdx.x) >> 4;
    int lane = threadIdx.x & 15;
    if (g >= E) return;
    int s = src[g], d = dst[g];
    ushort8 a = *((const ushort8*)(hn + (size_t)s * D) + lane);
    ushort8 c = *((const ushort8*)(hn + (size_t)d * D) + lane);
    float dot = 0.f;
#pragma unroll
    for (int t = 0; t < 8; ++t) dot += bf2f(a[t]) * bf2f(c[t]);
#pragma unroll
    for (int m = 8; m >= 1; m >>= 1) dot += __shfl_xor(dot, m);
    if (lane == 0) {
        float w = fmaxf(dot, 0.f);
        ew[g] = w;
        atomicAdd(deg + d, w);
        atomicAdd(cnt + d, 1);
    }
}

// deg -> dinv in place
__global__ __launch_bounds__(256) void dinv_kernel(float* __restrict__ deg, int N) {
    int i = blockIdx.x * 256 + threadIdx.x;
    if (i < N) {
        float dg = deg[i];
        deg[i] = (dg > 0.f) ? rsqrtf(fmaxf(dg, EPS)) : 0.f;
    }
}

// Single-WG exclusive scan of cnt -> rp (and pos copy). 4 elems/thread/chunk.
__global__ __launch_bounds__(1024) void scan_kernel(const int* __restrict__ cnt,
                                                    int* __restrict__ rp,
                                                    int* __restrict__ pos, int N) {
    __shared__ int wsum[16];
    __shared__ int stotal;
    int tid = threadIdx.x, lane = tid & 63, wv = tid >> 6;
    int carry = 0;
    int nq = N >> 2;                      // N divisible by 4
    for (int base = 0; base < nq; base += 1024) {
        int idx = base + tid;
        int4 c = make_int4(0, 0, 0, 0);
        if (idx < nq) c = ((const int4*)cnt)[idx];
        int tsum = c.x + c.y + c.z + c.w;
        int incl = tsum;
#pragma unroll
        for (int m = 1; m < 64; m <<= 1) {
            int t = __shfl_up(incl, m);
            if (lane >= m) incl += t;
        }
        __syncthreads();                  // protect previous iter's wsum reads
        if (lane == 63) wsum[wv] = incl;
        __syncthreads();
        if (tid == 0) {
            int acc = 0;
#pragma unroll
            for (int k = 0; k < 16; ++k) { int t = wsum[k]; wsum[k] = acc; acc += t; }
            stotal = acc;
        }
        __syncthreads();
        int excl = carry + wsum[wv] + incl - tsum;
        if (idx < nq) {
            int4 r;
            r.x = excl; r.y = excl + c.x; r.z = r.y + c.y; r.w = r.z + c.z;
            ((int4*)rp)[idx] = r;
            ((int4*)pos)[idx] = r;
        }
        carry += stotal;
    }
    if (tid == 0) rp[N] = carry;          // == E
}

// CSR fill: csr[idx] = (src, (1-a)*dinv[s]*w*dinv[d]) bucketed by dst
__global__ __launch_bounds__(256) void fill_kernel(const int* __restrict__ src,
                                                   const int* __restrict__ dst,
                                                   const float* __restrict__ ew,
                                                   const float* __restrict__ dinv,
                                                   const float* __restrict__ alpha,
                                                   int* __restrict__ pos,
                                                   int2* __restrict__ csr, int E) {
    int e = blockIdx.x * 256 + threadIdx.x;
    if (e >= E) return;
    int s = src[e], d = dst[e];
    int idx = atomicAdd(pos + d, 1);
    float w = (1.0f - alpha[0]) * dinv[s] * ew[e] * dinv[d];
    csr[idx] = make_int2(s, __float_as_int(w));
}

// One APPNP step, gather form, no atomics:
// zout[i] = a*fill[i] + (1-a)*dinv[i]^2*zin[i] + sum_e csrw*zin[csrsrc]
__global__ __launch_bounds__(256) void appnp_kernel(const int* __restrict__ rp,
                                                    const int2* __restrict__ csr,
                                                    const float* __restrict__ dinv,
                                                    const float* __restrict__ fill,
                                                    const float* __restrict__ zin,
                                                    const float* __restrict__ alpha,
                                                    float* __restrict__ zout, int N) {
    int i = blockIdx.x * 256 + threadIdx.x;
    if (i >= N) return;
    int beg = rp[i], end = rp[i + 1];
    float s = 0.f;
    for (int j = beg; j < end; ++j) {
        int2 p = csr[j];
        s += __int_as_float(p.y) * zin[p.x];
    }
    float al = alpha[0];
    float di = dinv[i];
    zout[i] = al * fill[i] + (1.0f - al) * di * di * zin[i] + s;
}

extern "C" void kernel_launch(void* const* d_in, const int* in_sizes, int n_in,
                              void* d_out, int out_size, void* d_ws, size_t ws_size,
                              hipStream_t stream) {
    const float* x     = (const float*)d_in[0];
    const float* mask  = (const float*)d_in[1];
    const int*   ei    = (const int*)d_in[2];
    const float* W     = (const float*)d_in[3];
    const float* b     = (const float*)d_in[4];
    const float* alpha = (const float*)d_in[5];

    int N = in_sizes[1];          // mask is N x 1
    int E = in_sizes[2] / 2;      // edge_index is 2 x E
    const int* src = ei;
    const int* dst = ei + E;

    float* out = (float*)d_out;   // [0,N) = z ; [N, N+E) = edge_weights
    float* ew  = out + N;

    // workspace layout (16B-aligned sections)
    char* wsb = (char*)d_ws;
    unsigned short* hn = (unsigned short*)wsb;                   // N*D bf16
    char* p = wsb + (size_t)N * D * 2;
    short* Wbf = (short*)p;            p += (size_t)D * D * 2;   // 32 KB
    float* deg  = (float*)p;           p += (size_t)N * 4;       // becomes dinv
    float* fill = (float*)p;           p += (size_t)N * 4;
    float* zA   = (float*)p;           p += (size_t)N * 4;
    float* zB   = (float*)p;           p += (size_t)N * 4;
    int*   cnt  = (int*)p;             p += (size_t)N * 4;
    int*   rp   = (int*)p;             p += (size_t)(N + 4) * 4;
    int*   pos  = (int*)p;             p += (size_t)N * 4;
    int2*  csr  = (int2*)p;                                      // E * 8 B

    int nb_n = (N + 255) / 256;
    int nb_e = (E + 255) / 256;
    int nb_eg = ((size_t)E * 16 + 255) / 256;   // one 16-lane group per edge

    convw_kernel<<<(D * D) / 256, 256, 0, stream>>>(W, Wbf);
    init_kernel<<<nb_n, 256, 0, stream>>>(mask, deg, fill, cnt, N);
    gemm_kernel<<<(N + 63) / 64, 256, 0, stream>>>(x, Wbf, b, hn, N);
    edge_kernel<<<nb_eg, 256, 0, stream>>>(src, dst, hn, ew, deg, cnt, E);
    dinv_kernel<<<nb_n, 256, 0, stream>>>(deg, N);
    scan_kernel<<<1, 1024, 0, stream>>>(cnt, rp, pos, N);
    fill_kernel<<<nb_e, 256, 0, stream>>>(src, dst, ew, deg, alpha, pos, csr, E);

    // z0 = fill; 5 gather steps ping-ponging zA/zB, last writes out directly
    appnp_kernel<<<nb_n, 256, 0, stream>>>(rp, csr, deg, fill, fill, alpha, zA, N);
    appnp_kernel<<<nb_n, 256, 0, stream>>>(rp, csr, deg, fill, zA,   alpha, zB, N);
    appnp_kernel<<<nb_n, 256, 0, stream>>>(rp, csr, deg, fill, zB,   alpha, zA, N);
    appnp_kernel<<<nb_n, 256, 0, stream>>>(rp, csr, deg, fill, zA,   alpha, zB, N);
    appnp_kernel<<<nb_n, 256, 0, stream>>>(rp, csr, deg, fill, zB,   alpha, out, N);
}